// Round 5
// baseline (366.923 us; speedup 1.0000x reference)
//
#include <hip/hip_runtime.h>
#include <cstdint>
#include <cstddef>

// Problem constants (Qwen3VLMoeTextExperts): E=8, H=2048, I=768, T=B*S=4096
#define NE 8
#define NH 2048
#define NI 768
#define NT 4096
#define NK2 6144   // NE*NI : K of second GEMM

typedef __bf16 bf16x8 __attribute__((ext_vector_type(8)));
typedef float f32x4 __attribute__((ext_vector_type(4)));
typedef unsigned short u16x8 __attribute__((ext_vector_type(8)));

__device__ __forceinline__ unsigned short f2bf(float f) {
  unsigned int u = __builtin_bit_cast(unsigned int, f);
  u += 0x7fffu + ((u >> 16) & 1u);   // round-to-nearest-even
  return (unsigned short)(u >> 16);
}

// async global->LDS, 16B per lane (dest must be linear: base + lane*16).
__device__ __forceinline__ void gload_lds16(const void* g, void* s) {
  __builtin_amdgcn_global_load_lds(
      (const __attribute__((address_space(1))) unsigned int*)g,
      (__attribute__((address_space(3))) unsigned int*)s, 16, 0, 0);
}

// ---------------- convert f32 -> bf16 (vectorized x8) ----------------
__global__ __launch_bounds__(256) void k_cvt(const float* __restrict__ in,
                                             unsigned short* __restrict__ out,
                                             long n) {
  long i = ((long)blockIdx.x * blockDim.x + threadIdx.x) * 8;
  if (i >= n) return;
  float4 f0 = *reinterpret_cast<const float4*>(in + i);
  float4 f1 = *reinterpret_cast<const float4*>(in + i + 4);
  u16x8 o;
  o[0] = f2bf(f0.x); o[1] = f2bf(f0.y); o[2] = f2bf(f0.z); o[3] = f2bf(f0.w);
  o[4] = f2bf(f1.x); o[5] = f2bf(f1.y); o[6] = f2bf(f1.z); o[7] = f2bf(f1.w);
  *reinterpret_cast<u16x8*>(out + i) = o;
}

// ------------- transpose + convert: out[b*oBS + perm(c)*oCS + r] = in[b][r][c] -------------
// mode 0: perm = identity. mode 1 (gate_up): interleave gate/up at 16-col
// granularity: gate col c -> (c>>4)*32 + (c&15); up col c -> (c>>4)*32 + 16 + (c&15).
__global__ __launch_bounds__(256) void k_transpose_cvt(
    const float* __restrict__ in, unsigned short* __restrict__ out,
    int R, int C, long inBS, long outBS, int outCS, int mode) {
  __shared__ float tile[32][33];
  const int b = blockIdx.z;
  const int r0 = blockIdx.y * 32, c0 = blockIdx.x * 32;
  const int tx = threadIdx.x, ty = threadIdx.y;
  const float* ib = in + (long)b * inBS;
#pragma unroll
  for (int d = 0; d < 4; d++)
    tile[ty + d * 8][tx] = ib[(long)(r0 + ty + d * 8) * C + c0 + tx];
  __syncthreads();
#pragma unroll
  for (int d = 0; d < 4; d++) {
    int c = c0 + ty + d * 8;   // original out-major index
    int r = r0 + tx;           // out minor index (coalesced)
    int orow;
    if (mode == 1) {
      int z = (c >= NI) ? 1 : 0;
      int cc = c - z * NI;
      orow = ((cc >> 4) << 5) + (z << 4) + (cc & 15);
    } else {
      orow = c;
    }
    out[(long)b * outBS + (long)orow * outCS + r] = f2bf(tile[tx][ty + d * 8]);
  }
}

// ==================== GEMM1: kk-split phases, minimal reads, 256x256 ====================
// BM=256 tokens, 256 B-rows (=128 inter cols), BK=64. 8 waves: wr=wave>>2 (M),
// wc=wave&3 (N). Per-wave out: rA(i)=(i>>2)*128+wr*64+(i&3)*16+fr (i<8),
// rB(j)=(j>>1)*128+wc*32+(j&1)*16+fr (j<4).
// Per K-tile: P1 = [stage T(k+1) full (8 gloads); vmcnt(8); barrier;
//                   read kk0 frags (12 ds_read_b128); 32 MFMA]
//             P2 = [read kk1 frags (12); barrier; 32 MFMA]
// Each LDS element read exactly once per wave (24 reads/tile, min). 2 barriers
// per tile. Stage targets are 2-phases-dead regions; duplicate stages at k=0
// and k=nkt-1 rewrite identical bytes (benign), keeping the vmcnt ledger
// uniform: at P1(k) after issue, outstanding = T(k)x8 older + T(k+1)x8 newer;
// vmcnt(8) certifies T(k) landed.
// Swizzle: chunk c of row r stored at c^(r&7); read key fr&7. 0 conflicts.

__global__ __launch_bounds__(512, 2) void k_gemm1(
    const unsigned short* __restrict__ Xb,    // [NT][NH] bf16
    const unsigned short* __restrict__ W1t,   // [NE][1536(perm)][NH] bf16
    const float* __restrict__ rw,             // [NT][NE]
    unsigned short* __restrict__ inter) {     // [NT][NK2] bf16
  __shared__ unsigned short ldsA[2][16384];   // 2 x 32 KiB
  __shared__ unsigned short ldsB[2][16384];   // 2 x 32 KiB

  const int e = blockIdx.z;
  const int t0 = blockIdx.y * 256;
  const int bn = blockIdx.x;
  const int tid = threadIdx.x;
  const int lane = tid & 63, wave = tid >> 6;
  const int wr = wave >> 2, wc = wave & 3;
  const int fr = lane & 15, fq = lane >> 4;
  const int nkt = NH / 64;                   // 32

  const unsigned short* Bg = W1t + (size_t)e * (2 * NI) * NH;
  const int rih = tid >> 3, ck = tid & 7;
  const unsigned short* sA = Xb + (size_t)(t0 + rih) * NH + ((ck ^ (rih & 7)) << 3);
  const unsigned short* sB = Bg + (size_t)(bn * 256 + rih) * NH + ((ck ^ (rih & 7)) << 3);
  const int dst = tid * 8;

#define STG1(C) do { \
    const int cc_ = (C); \
    unsigned short* da_ = &ldsA[cc_ & 1][dst]; \
    unsigned short* db_ = &ldsB[cc_ & 1][dst]; \
    const size_t ko_ = (size_t)cc_ * 64; \
    _Pragma("unroll") \
    for (int q = 0; q < 4; ++q) { \
      gload_lds16(sA + ko_ + (size_t)q * (64 * NH), da_ + q * 4096); \
      gload_lds16(sB + ko_ + (size_t)q * (64 * NH), db_ + q * 4096); \
    } \
  } while (0)

  f32x4 acc[8][4];
#pragma unroll
  for (int i = 0; i < 8; ++i)
#pragma unroll
    for (int j = 0; j < 4; ++j) acc[i][j] = (f32x4){0.f, 0.f, 0.f, 0.f};

  const int swz = fr & 7;
  int aoff[8], boff[4];
#pragma unroll
  for (int i = 0; i < 8; ++i)
    aoff[i] = ((i >> 2) * 128 + wr * 64 + (i & 3) * 16 + fr) * 64 + ((fq ^ swz) << 3);
#pragma unroll
  for (int j = 0; j < 4; ++j)
    boff[j] = ((j >> 1) * 128 + wc * 32 + (j & 1) * 16 + fr) * 64 + ((fq ^ swz) << 3);
  const int dk = ((((4 + fq) ^ swz) - (fq ^ swz)) << 3);   // kk=1 frag delta

  // prologue: stage T0, T1 (no waits; loop's first vmcnt covers)
  STG1(0);
  STG1(1);

  for (int kt = 0; kt < nkt; ++kt) {
    const int cur = kt & 1;
    const int nx = (kt + 1 < nkt) ? kt + 1 : nkt - 1;
    STG1(nx);
    asm volatile("s_waitcnt vmcnt(8)" ::: "memory");
    __builtin_amdgcn_sched_barrier(0);
    __builtin_amdgcn_s_barrier();
    __builtin_amdgcn_sched_barrier(0);
    {  // P1: kk = 0
      bf16x8 af[8], bf[4];
#pragma unroll
      for (int i = 0; i < 8; ++i)
        af[i] = *reinterpret_cast<const bf16x8*>(&ldsA[cur][aoff[i]]);
#pragma unroll
      for (int j = 0; j < 4; ++j)
        bf[j] = *reinterpret_cast<const bf16x8*>(&ldsB[cur][boff[j]]);
      __builtin_amdgcn_s_setprio(1);
#pragma unroll
      for (int i = 0; i < 8; ++i)
#pragma unroll
        for (int j = 0; j < 4; ++j)
          acc[i][j] = __builtin_amdgcn_mfma_f32_16x16x32_bf16(af[i], bf[j], acc[i][j], 0, 0, 0);
      __builtin_amdgcn_s_setprio(0);
    }
    {  // P2: kk = 1
      bf16x8 af[8], bf[4];
#pragma unroll
      for (int i = 0; i < 8; ++i)
        af[i] = *reinterpret_cast<const bf16x8*>(&ldsA[cur][aoff[i] + dk]);
#pragma unroll
      for (int j = 0; j < 4; ++j)
        bf[j] = *reinterpret_cast<const bf16x8*>(&ldsB[cur][boff[j] + dk]);
      __builtin_amdgcn_sched_barrier(0);
      __builtin_amdgcn_s_barrier();
      __builtin_amdgcn_sched_barrier(0);
      __builtin_amdgcn_s_setprio(1);
#pragma unroll
      for (int i = 0; i < 8; ++i)
#pragma unroll
        for (int j = 0; j < 4; ++j)
          acc[i][j] = __builtin_amdgcn_mfma_f32_16x16x32_bf16(af[i], bf[j], acc[i][j], 0, 0, 0);
      __builtin_amdgcn_s_setprio(0);
    }
  }
  asm volatile("s_waitcnt vmcnt(0)" ::: "memory");
#undef STG1

  // epilogue: silu(gate)*up*rw -> bf16.  acc[i][2p]=gate, acc[i][2p+1]=up for
  // inter col (within expert) = (p*4 + wc)*16 + fr; token row from rA(i).
#pragma unroll
  for (int i = 0; i < 8; ++i) {
    const int trow = t0 + (i >> 2) * 128 + wr * 64 + (i & 3) * 16 + fq * 4;
#pragma unroll
    for (int r = 0; r < 4; ++r) {
      const int t = trow + r;
      const float rwv = rw[(size_t)t * NE + e];
#pragma unroll
      for (int p = 0; p < 2; ++p) {
        float g = acc[i][2 * p][r];
        float u = acc[i][2 * p + 1][r];
        float s = g / (1.f + __expf(-g));  // silu
        const int col = bn * 128 + (p * 4 + wc) * 16 + fr;
        inter[(size_t)t * NK2 + e * NI + col] = f2bf(rwv * u * s);
      }
    }
  }
}

// ==================== GEMM2: same kk-split structure, 256x128 ====================
// 8 waves: wr=wave>>1 (4 M-slices of 64), wc=wave&1 (2 N-slices of 64).
// rA(i)=wr*64+i*16+fr (i<4), rB(j)=wc*64+j*16+fr (j<4). Per phase: 8 reads,
// 16 MFMA. Stage/tile: A 4 + B 2 gloads -> vmcnt(6). LDS 96 KiB.
__global__ __launch_bounds__(512, 2) void k_gemm2(
    const unsigned short* __restrict__ inter,  // [NT][NK2] bf16
    const unsigned short* __restrict__ W2t,    // [NH][NK2] bf16
    float* __restrict__ out) {                 // [NT][NH] f32
  __shared__ unsigned short ldsA[2][16384];    // 2 x 32 KiB (256x64)
  __shared__ unsigned short ldsB[2][8192];     // 2 x 16 KiB (128x64)

  const int t0 = blockIdx.y * 256;
  const int h0 = blockIdx.x * 128;
  const int tid = threadIdx.x;
  const int lane = tid & 63, wave = tid >> 6;
  const int wr = wave >> 1, wc = wave & 1;
  const int fr = lane & 15, fq = lane >> 4;
  const int nkt = NK2 / 64;                  // 96

  const int rih = tid >> 3, ck = tid & 7;
  const unsigned short* sA = inter + (size_t)(t0 + rih) * NK2 + ((ck ^ (rih & 7)) << 3);
  const unsigned short* sB = W2t + (size_t)(h0 + rih) * NK2 + ((ck ^ (rih & 7)) << 3);
  const int dst = tid * 8;

#define STG2(C) do { \
    const int cc_ = (C); \
    unsigned short* da_ = &ldsA[cc_ & 1][dst]; \
    unsigned short* db_ = &ldsB[cc_ & 1][dst]; \
    const size_t ko_ = (size_t)cc_ * 64; \
    _Pragma("unroll") \
    for (int q = 0; q < 4; ++q) \
      gload_lds16(sA + ko_ + (size_t)q * (64 * NK2), da_ + q * 4096); \
    _Pragma("unroll") \
    for (int q = 0; q < 2; ++q) \
      gload_lds16(sB + ko_ + (size_t)q * (64 * NK2), db_ + q * 4096); \
  } while (0)

  f32x4 acc[4][4];
#pragma unroll
  for (int i = 0; i < 4; ++i)
#pragma unroll
    for (int j = 0; j < 4; ++j) acc[i][j] = (f32x4){0.f, 0.f, 0.f, 0.f};

  const int swz = fr & 7;
  int aoff[4], boff[4];
#pragma unroll
  for (int i = 0; i < 4; ++i)
    aoff[i] = (wr * 64 + i * 16 + fr) * 64 + ((fq ^ swz) << 3);
#pragma unroll
  for (int j = 0; j < 4; ++j)
    boff[j] = (wc * 64 + j * 16 + fr) * 64 + ((fq ^ swz) << 3);
  const int dk = ((((4 + fq) ^ swz) - (fq ^ swz)) << 3);

  STG2(0);
  STG2(1);

  for (int kt = 0; kt < nkt; ++kt) {
    const int cur = kt & 1;
    const int nx = (kt + 1 < nkt) ? kt + 1 : nkt - 1;
    STG2(nx);
    asm volatile("s_waitcnt vmcnt(6)" ::: "memory");
    __builtin_amdgcn_sched_barrier(0);
    __builtin_amdgcn_s_barrier();
    __builtin_amdgcn_sched_barrier(0);
    {  // P1: kk = 0
      bf16x8 af[4], bf[4];
#pragma unroll
      for (int i = 0; i < 4; ++i)
        af[i] = *reinterpret_cast<const bf16x8*>(&ldsA[cur][aoff[i]]);
#pragma unroll
      for (int j = 0; j < 4; ++j)
        bf[j] = *reinterpret_cast<const bf16x8*>(&ldsB[cur][boff[j]]);
      __builtin_amdgcn_s_setprio(1);
#pragma unroll
      for (int i = 0; i < 4; ++i)
#pragma unroll
        for (int j = 0; j < 4; ++j)
          acc[i][j] = __builtin_amdgcn_mfma_f32_16x16x32_bf16(af[i], bf[j], acc[i][j], 0, 0, 0);
      __builtin_amdgcn_s_setprio(0);
    }
    {  // P2: kk = 1
      bf16x8 af[4], bf[4];
#pragma unroll
      for (int i = 0; i < 4; ++i)
        af[i] = *reinterpret_cast<const bf16x8*>(&ldsA[cur][aoff[i] + dk]);
#pragma unroll
      for (int j = 0; j < 4; ++j)
        bf[j] = *reinterpret_cast<const bf16x8*>(&ldsB[cur][boff[j] + dk]);
      __builtin_amdgcn_sched_barrier(0);
      __builtin_amdgcn_s_barrier();
      __builtin_amdgcn_sched_barrier(0);
      __builtin_amdgcn_s_setprio(1);
#pragma unroll
      for (int i = 0; i < 4; ++i)
#pragma unroll
        for (int j = 0; j < 4; ++j)
          acc[i][j] = __builtin_amdgcn_mfma_f32_16x16x32_bf16(af[i], bf[j], acc[i][j], 0, 0, 0);
      __builtin_amdgcn_s_setprio(0);
    }
  }
  asm volatile("s_waitcnt vmcnt(0)" ::: "memory");
#undef STG2

  const int rowBase = t0 + wr * 64 + fq * 4;
#pragma unroll
  for (int i = 0; i < 4; ++i)
#pragma unroll
    for (int j = 0; j < 4; ++j)
#pragma unroll
      for (int r = 0; r < 4; ++r)
        out[(size_t)(rowBase + i * 16 + r) * NH + h0 + wc * 64 + j * 16 + fr] =
            acc[i][j][r];
}

extern "C" void kernel_launch(void* const* d_in, const int* in_sizes, int n_in,
                              void* d_out, int out_size, void* d_ws, size_t ws_size,
                              hipStream_t stream) {
  const float* x = (const float*)d_in[0];    // [NT][NH]
  const float* rw = (const float*)d_in[1];   // [NT][NE]
  // d_in[2] router_indices: unused by reference (dense all-experts)
  const float* w1 = (const float*)d_in[3];   // [NE][NH][2*NI]
  const float* w2 = (const float*)d_in[4];   // [NE][NI][NH]
  float* out = (float*)d_out;

  char* ws = (char*)d_ws;
  // ws layout (bf16): Xb 16MB | W1t 48MB | W2t 24MB | inter 48MB  = 136 MiB
  unsigned short* Xb = (unsigned short*)ws;                               // [NT][NH]
  unsigned short* W1t = (unsigned short*)(ws + 16777216);                 // [NE][1536perm][NH]
  unsigned short* W2t = (unsigned short*)(ws + 16777216 + 50331648);      // [NH][NK2]
  unsigned short* inter = (unsigned short*)(ws + 16777216 + 50331648 + 25165824); // [NT][NK2]

  // 1) convert x
  k_cvt<<<dim3((NT * NH) / (256 * 8)), dim3(256), 0, stream>>>(x, Xb, (long)NT * NH);
  // 2) W1 [E][H][2I] -> W1t [E][perm(2I)][H], gate/up 16-interleaved
  k_transpose_cvt<<<dim3((2 * NI) / 32, NH / 32, NE), dim3(32, 8), 0, stream>>>(
      w1, W1t, NH, 2 * NI, (long)NH * 2 * NI, (long)2 * NI * NH, NH, 1);
  // 3) W2 [E][I][H] -> W2t [H][E*I]
  k_transpose_cvt<<<dim3(NH / 32, NI / 32, NE), dim3(32, 8), 0, stream>>>(
      w2, W2t, NI, NH, (long)NI * NH, (long)NI, NK2, 0);
  // 4) GEMM1 fused silu/up/rw -> inter (kk-split phases, 256x256)
  k_gemm1<<<dim3((2 * NI) / 256, NT / 256, NE), dim3(512), 0, stream>>>(Xb, W1t, rw, inter);
  // 5) GEMM2 -> out (kk-split phases, 256x128)
  k_gemm2<<<dim3(NH / 128, NT / 256), dim3(512), 0, stream>>>(inter, W2t, out);
}

// Round 6
// 366.742 us; speedup vs baseline: 1.0005x; 1.0005x over previous
//
#include <hip/hip_runtime.h>
#include <cstdint>
#include <cstddef>

// Problem constants (Qwen3VLMoeTextExperts): E=8, H=2048, I=768, T=B*S=4096
#define NE 8
#define NH 2048
#define NI 768
#define NT 4096
#define NK2 6144   // NE*NI : K of second GEMM

typedef __bf16 bf16x8 __attribute__((ext_vector_type(8)));
typedef float f32x4 __attribute__((ext_vector_type(4)));
typedef unsigned short u16x8 __attribute__((ext_vector_type(8)));

__device__ __forceinline__ unsigned short f2bf(float f) {
  unsigned int u = __builtin_bit_cast(unsigned int, f);
  u += 0x7fffu + ((u >> 16) & 1u);   // round-to-nearest-even
  return (unsigned short)(u >> 16);
}

// async global->LDS, 16B per lane (dest must be linear: base + lane*16).
__device__ __forceinline__ void gload_lds16(const void* g, void* s) {
  __builtin_amdgcn_global_load_lds(
      (const __attribute__((address_space(1))) unsigned int*)g,
      (__attribute__((address_space(3))) unsigned int*)s, 16, 0, 0);
}

// ---------------- convert f32 -> bf16 (vectorized x8) ----------------
__global__ __launch_bounds__(256) void k_cvt(const float* __restrict__ in,
                                             unsigned short* __restrict__ out,
                                             long n) {
  long i = ((long)blockIdx.x * blockDim.x + threadIdx.x) * 8;
  if (i >= n) return;
  float4 f0 = *reinterpret_cast<const float4*>(in + i);
  float4 f1 = *reinterpret_cast<const float4*>(in + i + 4);
  u16x8 o;
  o[0] = f2bf(f0.x); o[1] = f2bf(f0.y); o[2] = f2bf(f0.z); o[3] = f2bf(f0.w);
  o[4] = f2bf(f1.x); o[5] = f2bf(f1.y); o[6] = f2bf(f1.z); o[7] = f2bf(f1.w);
  *reinterpret_cast<u16x8*>(out + i) = o;
}

// ------------- transpose + convert: out[b*oBS + perm(c)*oCS + r] = in[b][r][c] -------------
// mode 0: perm = identity. mode 1 (gate_up): interleave gate/up at 16-col
// granularity: gate col c -> (c>>4)*32 + (c&15); up col c -> (c>>4)*32 + 16 + (c&15).
__global__ __launch_bounds__(256) void k_transpose_cvt(
    const float* __restrict__ in, unsigned short* __restrict__ out,
    int R, int C, long inBS, long outBS, int outCS, int mode) {
  __shared__ float tile[32][33];
  const int b = blockIdx.z;
  const int r0 = blockIdx.y * 32, c0 = blockIdx.x * 32;
  const int tx = threadIdx.x, ty = threadIdx.y;
  const float* ib = in + (long)b * inBS;
#pragma unroll
  for (int d = 0; d < 4; d++)
    tile[ty + d * 8][tx] = ib[(long)(r0 + ty + d * 8) * C + c0 + tx];
  __syncthreads();
#pragma unroll
  for (int d = 0; d < 4; d++) {
    int c = c0 + ty + d * 8;   // original out-major index
    int r = r0 + tx;           // out minor index (coalesced)
    int orow;
    if (mode == 1) {
      int z = (c >= NI) ? 1 : 0;
      int cc = c - z * NI;
      orow = ((cc >> 4) << 5) + (z << 4) + (cc & 15);
    } else {
      orow = c;
    }
    out[(long)b * outBS + (long)orow * outCS + r] = f2bf(tile[tx][ty + d * 8]);
  }
}

// ==================== GEMM1: 4 fine phases/tile + minimal reads, 256x256 ====================
// 8 waves: wr=wave>>2 (M), wc=wave&3 (N); per-wave out 128x64.
// rA(i)=(i>>2)*128+wr*64+(i&3)*16+fr, rB(j)=(j>>1)*128+wc*32+(j&1)*16+fr.
// Per K-tile k (cur=k&1), quadrant phases (IH,JH) in order (0,0)(0,1)(1,1)(1,0):
//  ph1: read af0(8)+bf0(4); STG_H0(k+1); vmcnt(4); bar; 16 MFMA
//  ph2: read bf1(4);        STG_H1(k+1);           bar; 16 MFMA
//  ph3: read af1(8);                               bar; 16 MFMA
//  ph4: read bf0'(4);                    vmcnt(4); bar; 16 MFMA
// 28 ds_read_b128/tile/wave (vs 40 in R4). Stage = half-tile (A+B rows 0-127
// or 128-255) = 4 gloads. vmcnt ledger: queue is exactly 8 at every wait;
// vmcnt(4) retires the 4 oldest = the half needed next; every half has
// 3 phases of HBM-latency cover. No trailing sched_barrier after MFMA so
// next-phase ds_reads can interleave into the MFMA cluster.
// Swizzle: chunk c of row r at c^(r&7), pre-swizzled global source; 0 conflicts.

__global__ __launch_bounds__(512, 1) void k_gemm1(
    const unsigned short* __restrict__ Xb,    // [NT][NH] bf16
    const unsigned short* __restrict__ W1t,   // [NE][1536(perm)][NH] bf16
    const float* __restrict__ rw,             // [NT][NE]
    unsigned short* __restrict__ inter) {     // [NT][NK2] bf16
  __shared__ unsigned short ldsA[2][16384];   // 2 x 32 KiB
  __shared__ unsigned short ldsB[2][16384];   // 2 x 32 KiB

  const int e = blockIdx.z;
  const int t0 = blockIdx.y * 256;
  const int bn = blockIdx.x;
  const int tid = threadIdx.x;
  const int lane = tid & 63, wave = tid >> 6;
  const int wr = wave >> 2, wc = wave & 3;
  const int fr = lane & 15, fq = lane >> 4;
  const int nkt = NH / 64;                   // 32

  const unsigned short* Bg = W1t + (size_t)e * (2 * NI) * NH;
  const int rih = tid >> 3, ck = tid & 7;
  const unsigned short* sA = Xb + (size_t)(t0 + rih) * NH + ((ck ^ (rih & 7)) << 3);
  const unsigned short* sB = Bg + (size_t)(bn * 256 + rih) * NH + ((ck ^ (rih & 7)) << 3);
  const int dst = tid * 8;

// half-tile stages: H0 = A/B rows 0-127 (q=0,1), H1 = rows 128-255 (q=2,3)
#define STG_H0(C) do { \
    const int cc_ = (C); const size_t ko_ = (size_t)cc_ * 64; \
    unsigned short* da_ = &ldsA[cc_ & 1][dst]; \
    unsigned short* db_ = &ldsB[cc_ & 1][dst]; \
    gload_lds16(sB + ko_, db_); \
    gload_lds16(sB + ko_ + (size_t)(64 * NH), db_ + 4096); \
    gload_lds16(sA + ko_, da_); \
    gload_lds16(sA + ko_ + (size_t)(64 * NH), da_ + 4096); \
  } while (0)
#define STG_H1(C) do { \
    const int cc_ = (C); const size_t ko_ = (size_t)cc_ * 64; \
    unsigned short* da_ = &ldsA[cc_ & 1][dst]; \
    unsigned short* db_ = &ldsB[cc_ & 1][dst]; \
    gload_lds16(sB + ko_ + (size_t)2 * (64 * NH), db_ + 8192); \
    gload_lds16(sB + ko_ + (size_t)3 * (64 * NH), db_ + 12288); \
    gload_lds16(sA + ko_ + (size_t)2 * (64 * NH), da_ + 8192); \
    gload_lds16(sA + ko_ + (size_t)3 * (64 * NH), da_ + 12288); \
  } while (0)
#define WAITV4 asm volatile("s_waitcnt vmcnt(4)" ::: "memory")
#define BAR do { __builtin_amdgcn_sched_barrier(0); \
                 __builtin_amdgcn_s_barrier(); \
                 __builtin_amdgcn_sched_barrier(0); } while (0)

  f32x4 acc[8][4];
#pragma unroll
  for (int i = 0; i < 8; ++i)
#pragma unroll
    for (int j = 0; j < 4; ++j) acc[i][j] = (f32x4){0.f, 0.f, 0.f, 0.f};

  const int swz = fr & 7;
  int aoff[8], boff[4];
#pragma unroll
  for (int i = 0; i < 8; ++i)
    aoff[i] = ((i >> 2) * 128 + wr * 64 + (i & 3) * 16 + fr) * 64 + ((fq ^ swz) << 3);
#pragma unroll
  for (int j = 0; j < 4; ++j)
    boff[j] = ((j >> 1) * 128 + wc * 32 + (j & 1) * 16 + fr) * 64 + ((fq ^ swz) << 3);
  const int dk = ((((4 + fq) ^ swz) - (fq ^ swz)) << 3);   // kk=1 frag delta

  // prologue: stage tile 0 (both halves); certify H0(0); barrier
  STG_H0(0);
  STG_H1(0);
  WAITV4;
  BAR;

  for (int kt = 0; kt < nkt; ++kt) {
    const int cur = kt & 1;
    const int nx = (kt + 1 < nkt) ? kt + 1 : nkt - 1;
    const unsigned short* lA = ldsA[cur];
    const unsigned short* lB = ldsB[cur];
    bf16x8 af0[4][2], af1[4][2], bf0[2][2], bf1[2][2];

    // ---- ph1: (IH0,JH0) ----
#pragma unroll
    for (int m = 0; m < 4; ++m) {
      af0[m][0] = *reinterpret_cast<const bf16x8*>(lA + aoff[m]);
      af0[m][1] = *reinterpret_cast<const bf16x8*>(lA + aoff[m] + dk);
    }
#pragma unroll
    for (int jj = 0; jj < 2; ++jj) {
      bf0[jj][0] = *reinterpret_cast<const bf16x8*>(lB + boff[jj]);
      bf0[jj][1] = *reinterpret_cast<const bf16x8*>(lB + boff[jj] + dk);
    }
    STG_H0(nx);
    WAITV4;
    BAR;
    __builtin_amdgcn_s_setprio(1);
#pragma unroll
    for (int kk = 0; kk < 2; ++kk)
#pragma unroll
      for (int m = 0; m < 4; ++m)
#pragma unroll
        for (int jj = 0; jj < 2; ++jj)
          acc[m][jj] = __builtin_amdgcn_mfma_f32_16x16x32_bf16(af0[m][kk], bf0[jj][kk], acc[m][jj], 0, 0, 0);
    __builtin_amdgcn_s_setprio(0);

    // ---- ph2: (IH0,JH1) ----
#pragma unroll
    for (int jj = 0; jj < 2; ++jj) {
      bf1[jj][0] = *reinterpret_cast<const bf16x8*>(lB + boff[2 + jj]);
      bf1[jj][1] = *reinterpret_cast<const bf16x8*>(lB + boff[2 + jj] + dk);
    }
    STG_H1(nx);
    BAR;
    __builtin_amdgcn_s_setprio(1);
#pragma unroll
    for (int kk = 0; kk < 2; ++kk)
#pragma unroll
      for (int m = 0; m < 4; ++m)
#pragma unroll
        for (int jj = 0; jj < 2; ++jj)
          acc[m][2 + jj] = __builtin_amdgcn_mfma_f32_16x16x32_bf16(af0[m][kk], bf1[jj][kk], acc[m][2 + jj], 0, 0, 0);
    __builtin_amdgcn_s_setprio(0);

    // ---- ph3: (IH1,JH1) ----
#pragma unroll
    for (int m = 0; m < 4; ++m) {
      af1[m][0] = *reinterpret_cast<const bf16x8*>(lA + aoff[4 + m]);
      af1[m][1] = *reinterpret_cast<const bf16x8*>(lA + aoff[4 + m] + dk);
    }
    BAR;
    __builtin_amdgcn_s_setprio(1);
#pragma unroll
    for (int kk = 0; kk < 2; ++kk)
#pragma unroll
      for (int m = 0; m < 4; ++m)
#pragma unroll
        for (int jj = 0; jj < 2; ++jj)
          acc[4 + m][2 + jj] = __builtin_amdgcn_mfma_f32_16x16x32_bf16(af1[m][kk], bf1[jj][kk], acc[4 + m][2 + jj], 0, 0, 0);
    __builtin_amdgcn_s_setprio(0);

    // ---- ph4: (IH1,JH0) ----
#pragma unroll
    for (int jj = 0; jj < 2; ++jj) {
      bf0[jj][0] = *reinterpret_cast<const bf16x8*>(lB + boff[jj]);
      bf0[jj][1] = *reinterpret_cast<const bf16x8*>(lB + boff[jj] + dk);
    }
    WAITV4;
    BAR;
    __builtin_amdgcn_s_setprio(1);
#pragma unroll
    for (int kk = 0; kk < 2; ++kk)
#pragma unroll
      for (int m = 0; m < 4; ++m)
#pragma unroll
        for (int jj = 0; jj < 2; ++jj)
          acc[4 + m][jj] = __builtin_amdgcn_mfma_f32_16x16x32_bf16(af1[m][kk], bf0[jj][kk], acc[4 + m][jj], 0, 0, 0);
    __builtin_amdgcn_s_setprio(0);
  }
  asm volatile("s_waitcnt vmcnt(0)" ::: "memory");
#undef STG_H0
#undef STG_H1
#undef WAITV4
#undef BAR

  // epilogue: silu(gate)*up*rw -> bf16.  acc[i][2p]=gate, acc[i][2p+1]=up for
  // inter col (within expert) = (p*4 + wc)*16 + fr; token row from rA(i).
#pragma unroll
  for (int i = 0; i < 8; ++i) {
    const int trow = t0 + (i >> 2) * 128 + wr * 64 + (i & 3) * 16 + fq * 4;
#pragma unroll
    for (int r = 0; r < 4; ++r) {
      const int t = trow + r;
      const float rwv = rw[(size_t)t * NE + e];
#pragma unroll
      for (int p = 0; p < 2; ++p) {
        float g = acc[i][2 * p][r];
        float u = acc[i][2 * p + 1][r];
        float s = g / (1.f + __expf(-g));  // silu
        const int col = bn * 128 + (p * 4 + wc) * 16 + fr;
        inter[(size_t)t * NK2 + e * NI + col] = f2bf(rwv * u * s);
      }
    }
  }
}

// ==================== GEMM2: kk-split structure (unchanged from R5), 256x128 ====================
__global__ __launch_bounds__(512, 2) void k_gemm2(
    const unsigned short* __restrict__ inter,  // [NT][NK2] bf16
    const unsigned short* __restrict__ W2t,    // [NH][NK2] bf16
    float* __restrict__ out) {                 // [NT][NH] f32
  __shared__ unsigned short ldsA[2][16384];    // 2 x 32 KiB (256x64)
  __shared__ unsigned short ldsB[2][8192];     // 2 x 16 KiB (128x64)

  const int t0 = blockIdx.y * 256;
  const int h0 = blockIdx.x * 128;
  const int tid = threadIdx.x;
  const int lane = tid & 63, wave = tid >> 6;
  const int wr = wave >> 1, wc = wave & 1;
  const int fr = lane & 15, fq = lane >> 4;
  const int nkt = NK2 / 64;                  // 96

  const int rih = tid >> 3, ck = tid & 7;
  const unsigned short* sA = inter + (size_t)(t0 + rih) * NK2 + ((ck ^ (rih & 7)) << 3);
  const unsigned short* sB = W2t + (size_t)(h0 + rih) * NK2 + ((ck ^ (rih & 7)) << 3);
  const int dst = tid * 8;

#define STG2(C) do { \
    const int cc_ = (C); \
    unsigned short* da_ = &ldsA[cc_ & 1][dst]; \
    unsigned short* db_ = &ldsB[cc_ & 1][dst]; \
    const size_t ko_ = (size_t)cc_ * 64; \
    _Pragma("unroll") \
    for (int q = 0; q < 4; ++q) \
      gload_lds16(sA + ko_ + (size_t)q * (64 * NK2), da_ + q * 4096); \
    _Pragma("unroll") \
    for (int q = 0; q < 2; ++q) \
      gload_lds16(sB + ko_ + (size_t)q * (64 * NK2), db_ + q * 4096); \
  } while (0)

  f32x4 acc[4][4];
#pragma unroll
  for (int i = 0; i < 4; ++i)
#pragma unroll
    for (int j = 0; j < 4; ++j) acc[i][j] = (f32x4){0.f, 0.f, 0.f, 0.f};

  const int swz = fr & 7;
  int aoff[4], boff[4];
#pragma unroll
  for (int i = 0; i < 4; ++i)
    aoff[i] = (wr * 64 + i * 16 + fr) * 64 + ((fq ^ swz) << 3);
#pragma unroll
  for (int j = 0; j < 4; ++j)
    boff[j] = (wc * 64 + j * 16 + fr) * 64 + ((fq ^ swz) << 3);
  const int dk = ((((4 + fq) ^ swz) - (fq ^ swz)) << 3);

  STG2(0);
  STG2(1);

  for (int kt = 0; kt < nkt; ++kt) {
    const int cur = kt & 1;
    const int nx = (kt + 1 < nkt) ? kt + 1 : nkt - 1;
    STG2(nx);
    asm volatile("s_waitcnt vmcnt(6)" ::: "memory");
    __builtin_amdgcn_sched_barrier(0);
    __builtin_amdgcn_s_barrier();
    __builtin_amdgcn_sched_barrier(0);
    {  // P1: kk = 0
      bf16x8 af[4], bf[4];
#pragma unroll
      for (int i = 0; i < 4; ++i)
        af[i] = *reinterpret_cast<const bf16x8*>(&ldsA[cur][aoff[i]]);
#pragma unroll
      for (int j = 0; j < 4; ++j)
        bf[j] = *reinterpret_cast<const bf16x8*>(&ldsB[cur][boff[j]]);
      __builtin_amdgcn_s_setprio(1);
#pragma unroll
      for (int i = 0; i < 4; ++i)
#pragma unroll
        for (int j = 0; j < 4; ++j)
          acc[i][j] = __builtin_amdgcn_mfma_f32_16x16x32_bf16(af[i], bf[j], acc[i][j], 0, 0, 0);
      __builtin_amdgcn_s_setprio(0);
    }
    {  // P2: kk = 1
      bf16x8 af[4], bf[4];
#pragma unroll
      for (int i = 0; i < 4; ++i)
        af[i] = *reinterpret_cast<const bf16x8*>(&ldsA[cur][aoff[i] + dk]);
#pragma unroll
      for (int j = 0; j < 4; ++j)
        bf[j] = *reinterpret_cast<const bf16x8*>(&ldsB[cur][boff[j] + dk]);
      __builtin_amdgcn_sched_barrier(0);
      __builtin_amdgcn_s_barrier();
      __builtin_amdgcn_sched_barrier(0);
      __builtin_amdgcn_s_setprio(1);
#pragma unroll
      for (int i = 0; i < 4; ++i)
#pragma unroll
        for (int j = 0; j < 4; ++j)
          acc[i][j] = __builtin_amdgcn_mfma_f32_16x16x32_bf16(af[i], bf[j], acc[i][j], 0, 0, 0);
      __builtin_amdgcn_s_setprio(0);
    }
  }
  asm volatile("s_waitcnt vmcnt(0)" ::: "memory");
#undef STG2

  const int rowBase = t0 + wr * 64 + fq * 4;
#pragma unroll
  for (int i = 0; i < 4; ++i)
#pragma unroll
    for (int j = 0; j < 4; ++j)
#pragma unroll
      for (int r = 0; r < 4; ++r)
        out[(size_t)(rowBase + i * 16 + r) * NH + h0 + wc * 64 + j * 16 + fr] =
            acc[i][j][r];
}

extern "C" void kernel_launch(void* const* d_in, const int* in_sizes, int n_in,
                              void* d_out, int out_size, void* d_ws, size_t ws_size,
                              hipStream_t stream) {
  const float* x = (const float*)d_in[0];    // [NT][NH]
  const float* rw = (const float*)d_in[1];   // [NT][NE]
  // d_in[2] router_indices: unused by reference (dense all-experts)
  const float* w1 = (const float*)d_in[3];   // [NE][NH][2*NI]
  const float* w2 = (const float*)d_in[4];   // [NE][NI][NH]
  float* out = (float*)d_out;

  char* ws = (char*)d_ws;
  // ws layout (bf16): Xb 16MB | W1t 48MB | W2t 24MB | inter 48MB  = 136 MiB
  unsigned short* Xb = (unsigned short*)ws;                               // [NT][NH]
  unsigned short* W1t = (unsigned short*)(ws + 16777216);                 // [NE][1536perm][NH]
  unsigned short* W2t = (unsigned short*)(ws + 16777216 + 50331648);      // [NH][NK2]
  unsigned short* inter = (unsigned short*)(ws + 16777216 + 50331648 + 25165824); // [NT][NK2]

  // 1) convert x
  k_cvt<<<dim3((NT * NH) / (256 * 8)), dim3(256), 0, stream>>>(x, Xb, (long)NT * NH);
  // 2) W1 [E][H][2I] -> W1t [E][perm(2I)][H], gate/up 16-interleaved
  k_transpose_cvt<<<dim3((2 * NI) / 32, NH / 32, NE), dim3(32, 8), 0, stream>>>(
      w1, W1t, NH, 2 * NI, (long)NH * 2 * NI, (long)2 * NI * NH, NH, 1);
  // 3) W2 [E][I][H] -> W2t [H][E*I]
  k_transpose_cvt<<<dim3(NH / 32, NI / 32, NE), dim3(32, 8), 0, stream>>>(
      w2, W2t, NI, NH, (long)NI * NH, (long)NI, NK2, 0);
  // 4) GEMM1 fused silu/up/rw -> inter (4 fine phases + minimal reads, 256x256)
  k_gemm1<<<dim3((2 * NI) / 256, NT / 256, NE), dim3(512), 0, stream>>>(Xb, W1t, rw, inter);
  // 5) GEMM2 -> out (kk-split phases, 256x128)
  k_gemm2<<<dim3(NH / 128, NT / 256), dim3(512), 0, stream>>>(inter, W2t, out);
}